// Round 16
// baseline (68.937 us; speedup 1.0000x reference)
//
#include <hip/hip_runtime.h>

#define NROWS 65536
#define DIM   64
#define NE    512

// d_out is FLOAT32: [ z_q (4194304) | indices-as-float (65536) | loss (1) ]
// Scratch in d_ws (~139 KB used):
//   preSplit: 16 planes x 512 rows x 16B. plane_id = kt*4 + hh*2 + part
//             (part 0 = (-2e)_hi, 1 = (-2e)_lo). Contiguous-per-tile reads.
#define WS_PRESPLIT 0
#define WS_PREY     131072   // 512 x 16B: (ynorm_hi, ynorm_lo, 0...)
#define WS_YNORM    139264   // 512 x f32 np-pairwise ||e||^2
#define WS_ACC      141312   // u64 fixed-point loss accumulator
#define WS_TICKET   141320   // u32 completion ticket

typedef __attribute__((ext_vector_type(8)))  short bf16x8;
typedef __attribute__((ext_vector_type(16))) float f32x16;

static __device__ __forceinline__ unsigned short bf16rne(float x) {
    unsigned int u = __float_as_uint(x);
    u += 0x7FFFu + ((u >> 16) & 1u);            // RNE (finite inputs only)
    return (unsigned short)(u >> 16);
}
static __device__ __forceinline__ float bf16tof(unsigned short h) {
    return __uint_as_float(((unsigned int)h) << 16);
}

// K0: codebook prep (512 rows, 2 blocks) into plane layout; zero acc/ticket.
__global__ __launch_bounds__(256) void vq_prep(
    const float* __restrict__ ew, char* ws)
{
    const int r = blockIdx.x * 256 + threadIdx.x;     // 0..511
    if (r == 0) {
        *(unsigned long long*)(ws + WS_ACC)    = 0ull;
        *(unsigned long long*)(ws + WS_TICKET) = 0ull;
    }
    float a[64];
    const float4* src = (const float4*)(ew + (size_t)r * DIM);
    #pragma unroll
    for (int q = 0; q < 16; ++q) {
        float4 v = src[q];
        a[q*4+0]=v.x; a[q*4+1]=v.y; a[q*4+2]=v.z; a[q*4+3]=v.w;
    }
    // numpy-pairwise ||e||^2 (exact np f32 order)
    float rc[8];
    #pragma unroll
    for (int j = 0; j < 8; ++j) rc[j] = __fmul_rn(a[j], a[j]);
    #pragma unroll
    for (int i = 8; i < 64; i += 8)
        #pragma unroll
        for (int j = 0; j < 8; ++j)
            rc[j] = __fadd_rn(rc[j], __fmul_rn(a[i+j], a[i+j]));
    float Y = __fadd_rn(__fadd_rn(__fadd_rn(rc[0],rc[1]),__fadd_rn(rc[2],rc[3])),
                        __fadd_rn(__fadd_rn(rc[4],rc[5]),__fadd_rn(rc[6],rc[7])));
    ((float*)(ws + WS_YNORM))[r] = Y;
    unsigned short ynh = bf16rne(Y);
    unsigned short ynl = bf16rne(Y - bf16tof(ynh));
    bf16x8 py = {};
    py[0] = (short)ynh; py[1] = (short)ynl;
    *(bf16x8*)(ws + WS_PREY + r*16) = py;
    // (-2e) split-bf16 into planes: element block kt*16 + hh*8 + j
    #pragma unroll
    for (int c = 0; c < 8; ++c) {        // c = kt*2 + hh
        bf16x8 h, l;
        #pragma unroll
        for (int j = 0; j < 8; ++j) {
            float x = -2.0f * a[c*8+j];
            unsigned short hb = bf16rne(x);
            h[j] = (short)hb;
            l[j] = (short)bf16rne(x - bf16tof(hb));
        }
        int kt = c >> 1, hhp = c & 1;
        int plane = kt*4 + hhp*2;
        *(bf16x8*)(ws + WS_PRESPLIT + (size_t)plane*8192 + r*16)       = h;
        *(bf16x8*)(ws + WS_PRESPLIT + (size_t)(plane+1)*8192 + r*16)   = l;
    }
}

// K1: 256 blocks x 1024 threads (16 waves). Block owns 256 z-rows.
// Wave wv: row group rg=wv>>2 (64 rows = 2 MFMA B-sets), embed quarter
// eh=wv&3 (128 embeds = 4 tiles). Each A-fragment feeds 6 MFMAs (ILP 2).
__global__ __launch_bounds__(1024) void vq_fused(
    const float* __restrict__ z, const float* __restrict__ ew,
    char* ws, float* out)
{
    __shared__ __align__(16) char ldsA[131072];   // 16 planes x [512][16B]
    __shared__ __align__(16) char ldsY[8192];     // preY fragments
    __shared__ float4 mrg[4][256];
    __shared__ int    rwin[256];
    __shared__ float  rdist[256];
    __shared__ float  rX[256];
    __shared__ float  zs[64];
    __shared__ float  rd8[8];
    __shared__ int    ri8[8];
    __shared__ unsigned int flagbits[8];
    __shared__ float  wred[4];

    const int tid  = threadIdx.x;
    const int lane = tid & 63;
    const int wv   = tid >> 6;       // 0..15
    const int rg   = wv >> 2;        // 0..3: 64-row group
    const int eh   = wv & 3;         // 0..3: embed quarter
    const int hh   = lane >> 5;
    const int l31  = lane & 31;
    const int R0   = blockIdx.x * 256;
    const int eoff = eh * 128;

    if (tid < 8) flagbits[tid] = 0u;

    // ---- z fragments for 2 row-sets (split-bf16) + per-set sum-sq ----
    bf16x8 zh0[4], zl0[4], zh1[4], zl1[4];
    float xacc_a = 0.f, xacc_b = 0.f;
    {
        const float* zpA = z + (size_t)(R0 + rg*64 + l31) * DIM + hh * 8;
        const float* zpB = zpA + 32 * DIM;
        #pragma unroll
        for (int kt = 0; kt < 4; ++kt) {
            float4 p0 = *(const float4*)(zpA + kt*16);
            float4 p1 = *(const float4*)(zpA + kt*16 + 4);
            float4 q0 = *(const float4*)(zpB + kt*16);
            float4 q1 = *(const float4*)(zpB + kt*16 + 4);
            float aA[8] = {p0.x,p0.y,p0.z,p0.w,p1.x,p1.y,p1.z,p1.w};
            float aB[8] = {q0.x,q0.y,q0.z,q0.w,q1.x,q1.y,q1.z,q1.w};
            bf16x8 hA, lA, hB, lB;
            #pragma unroll
            for (int j = 0; j < 8; ++j) {
                unsigned short hb = bf16rne(aA[j]);
                hA[j] = (short)hb;
                lA[j] = (short)bf16rne(aA[j] - bf16tof(hb));
                xacc_a = fmaf(aA[j], aA[j], xacc_a);
                unsigned short hc = bf16rne(aB[j]);
                hB[j] = (short)hc;
                lB[j] = (short)bf16rne(aB[j] - bf16tof(hc));
                xacc_b = fmaf(aB[j], aB[j], xacc_b);
            }
            zh0[kt] = hA; zl0[kt] = lA;
            zh1[kt] = hB; zl1[kt] = lB;
        }
    }

    // ---- stage preSplit+preY (139264 B = 8704 x 16B), register-lean ----
    #pragma unroll 1
    for (int i = 0; i < 9; ++i) {
        int idx = tid + 1024 * i;
        if (idx < 8704) {
            float4 v = *(const float4*)(ws + idx*16);
            if (idx < 8192) *(float4*)(ldsA + idx*16) = v;
            else            *(float4*)(ldsY + (idx - 8192)*16) = v;
        }
    }
    __syncthreads();

    const bf16x8 zero8 = {};
    bf16x8 bones = {};
    if (hh == 0) { bones[0] = (short)0x3F80; bones[1] = (short)0x3F80; }

    float d1a = 3.4e38f, d2a = 3.4e38f, d1b = 3.4e38f, d2b = 3.4e38f;
    int   i1a = 0, i1b = 0;

    // ---- main loop: 4 tiles of 32 embeds; conflict-free plane reads ----
    #pragma unroll 1
    for (int t = 0; t < 4; ++t) {
        const int e0   = eoff + t*32;
        const int arow = e0 + l31;

        f32x16 acc0, acc1;
        #pragma unroll
        for (int g = 0; g < 16; ++g) { acc0[g] = 0.f; acc1[g] = 0.f; }

        bf16x8 ay = zero8;
        if (hh == 0) ay = *(const bf16x8*)(ldsY + arow*16);
        acc0 = __builtin_amdgcn_mfma_f32_32x32x16_bf16(ay, bones, acc0, 0,0,0);
        acc1 = __builtin_amdgcn_mfma_f32_32x32x16_bf16(ay, bones, acc1, 0,0,0);

        #pragma unroll
        for (int kt = 0; kt < 4; ++kt) {
            const char* pb = ldsA + (size_t)(kt*4 + hh*2)*8192 + arow*16;
            bf16x8 ah = *(const bf16x8*)(pb);
            bf16x8 al = *(const bf16x8*)(pb + 8192);
            acc0 = __builtin_amdgcn_mfma_f32_32x32x16_bf16(ah, zh0[kt], acc0, 0,0,0);
            acc1 = __builtin_amdgcn_mfma_f32_32x32x16_bf16(ah, zh1[kt], acc1, 0,0,0);
            acc0 = __builtin_amdgcn_mfma_f32_32x32x16_bf16(ah, zl0[kt], acc0, 0,0,0);
            acc1 = __builtin_amdgcn_mfma_f32_32x32x16_bf16(ah, zl1[kt], acc1, 0,0,0);
            acc0 = __builtin_amdgcn_mfma_f32_32x32x16_bf16(al, zh0[kt], acc0, 0,0,0);
            acc1 = __builtin_amdgcn_mfma_f32_32x32x16_bf16(al, zh1[kt], acc1, 0,0,0);
        }

        const int ebase = e0 + 4*hh;
        #pragma unroll
        for (int g = 0; g < 16; ++g) {
            int e = ebase + (g & 3) + 8*(g >> 2);
            float da = acc0[g], db = acc1[g];
            d2a = fminf(fmaxf(da, d1a), d2a);
            bool ba = da < d1a; i1a = ba ? e : i1a; d1a = fminf(da, d1a);
            d2b = fminf(fmaxf(db, d1b), d2b);
            bool bb = db < d1b; i1b = bb ? e : i1b; d1b = fminf(db, d1b);
        }
    }

    // ---- intra-wave hh merge (both row-sets) ----
    float s1a, s2a, s1b, s2b, Xa, Xb;
    int   wia, wib;
    {
        float od1 = __shfl_xor(d1a, 32, 64);
        int   oi1 = __shfl_xor(i1a, 32, 64);
        float od2 = __shfl_xor(d2a, 32, 64);
        bool  oth = (od1 < d1a) || (od1 == d1a && oi1 < i1a);
        wia = oth ? oi1 : i1a;
        s1a = fminf(d1a, od1);
        s2a = fminf(fmaxf(d1a, od1), fminf(d2a, od2));
        Xa  = xacc_a + __shfl_xor(xacc_a, 32, 64);
    }
    {
        float od1 = __shfl_xor(d1b, 32, 64);
        int   oi1 = __shfl_xor(i1b, 32, 64);
        float od2 = __shfl_xor(d2b, 32, 64);
        bool  oth = (od1 < d1b) || (od1 == d1b && oi1 < i1b);
        wib = oth ? oi1 : i1b;
        s1b = fminf(d1b, od1);
        s2b = fminf(fmaxf(d1b, od1), fminf(d2b, od2));
        Xb  = xacc_b + __shfl_xor(xacc_b, 32, 64);
    }

    // ---- post per-quarter results; 4-way merge by eh==0 waves ----
    if (hh == 0) {
        mrg[eh][rg*64 + l31]      = make_float4(s1a, __int_as_float(wia), s2a, 0.f);
        mrg[eh][rg*64 + 32 + l31] = make_float4(s1b, __int_as_float(wib), s2b, 0.f);
    }
    __syncthreads();
    if (eh == 0 && hh == 0) {
        #pragma unroll
        for (int s = 0; s < 2; ++s) {
            int   r = rg*64 + s*32 + l31;
            float X = s ? Xb : Xa;
            float s1 = 3.4e38f, s2 = 3.4e38f;
            int   i1 = 0;
            #pragma unroll
            for (int q = 0; q < 4; ++q) {     // ascending embed quarters
                float4 v = mrg[q][r];
                if (v.x < s1) { s2 = fminf(s1, v.z); s1 = v.x; i1 = __float_as_int(v.y); }
                else          { s2 = fminf(s2, v.x); }
            }
            float Xs = X + 1e-3f;
            float ue = __uint_as_float(__float_as_uint(Xs) & 0x7F800000u) * 1.1920929e-7f;
            bool  flag = (s2 - s1) < (2.0f * ue + 2e-6f);
            rwin[r]  = i1;
            rdist[r] = s1;
            rX[r]    = X;
            if (flag) atomicOr(&flagbits[r >> 5], 1u << (r & 31));
        }
    }
    __syncthreads();

    // ---- rescan flagged rows (np-f32 exact; 512 threads, 1 embed each) ----
    const float* yn = (const float*)(ws + WS_YNORM);
    for (int g8 = 0; g8 < 8; ++g8) {
        unsigned bits = flagbits[g8];
        while (bits) {
            int r = g8*32 + __ffs(bits) - 1;
            bits &= bits - 1;
            if (tid < 16)
                *(float4*)(zs + tid*4) =
                    *(const float4*)(z + (size_t)(R0 + r) * DIM + tid*4);
            __syncthreads();
            float rc[8];
            #pragma unroll
            for (int j = 0; j < 8; ++j) rc[j] = __fmul_rn(zs[j], zs[j]);
            #pragma unroll
            for (int i = 8; i < 64; i += 8)
                #pragma unroll
                for (int j = 0; j < 8; ++j)
                    rc[j] = __fadd_rn(rc[j], __fmul_rn(zs[i+j], zs[i+j]));
            float xn = __fadd_rn(__fadd_rn(__fadd_rn(rc[0],rc[1]),__fadd_rn(rc[2],rc[3])),
                                 __fadd_rn(__fadd_rn(rc[4],rc[5]),__fadd_rn(rc[6],rc[7])));
            float bd = 3.4e38f; int bi = NE;
            if (tid < NE) {
                const int e = tid;
                const float* ep = ew + (size_t)e * DIM;
                double m0 = 0.0, m1 = 0.0, m2 = 0.0, m3 = 0.0;
                #pragma unroll
                for (int q = 0; q < 16; ++q) {
                    float4 ev = *(const float4*)(ep + q*4);
                    m0 = fma((double)zs[q*4+0], (double)ev.x, m0);
                    m1 = fma((double)zs[q*4+1], (double)ev.y, m1);
                    m2 = fma((double)zs[q*4+2], (double)ev.z, m2);
                    m3 = fma((double)zs[q*4+3], (double)ev.w, m3);
                }
                double m = (m0 + m1) + (m2 + m3);
                float W = __fadd_rn(xn, yn[e]);
                float d = __fadd_rn(W, -(2.0f * (float)m));
                bd = d; bi = e;
            }
            #pragma unroll
            for (int off = 32; off >= 1; off >>= 1) {
                float od = __shfl_xor(bd, off, 64);
                int   oi = __shfl_xor(bi, off, 64);
                if (od < bd || (od == bd && oi < bi)) { bd = od; bi = oi; }
            }
            if (lane == 0 && wv < 8) { rd8[wv] = bd; ri8[wv] = bi; }
            __syncthreads();
            if (tid == 0) {
                float fd = rd8[0]; int fi = ri8[0];
                #pragma unroll
                for (int k = 1; k < 8; ++k)
                    if (rd8[k] < fd || (rd8[k] == fd && ri8[k] < fi)) { fd = rd8[k]; fi = ri8[k]; }
                rwin[r]  = fi;
                rdist[r] = fd;     // full np distance (includes X)
                rX[r]    = 0.f;    // no double count in loss
            }
            __syncthreads();
        }
    }

    // ---- index write (coalesced 256 floats) ----
    if (tid < 256)
        out[(size_t)NROWS*DIM + R0 + tid] = (float)rwin[tid];

    // ---- z_q write: 256 rows x 16 float4 = 4096 float4 over 1024 threads ----
    #pragma unroll
    for (int i = 0; i < 4; ++i) {
        int f4  = tid + 1024 * i;         // 0..4095
        int row = f4 >> 4;                // 0..255
        int c4  = f4 & 15;
        float4 v = *(const float4*)(ew + (size_t)rwin[row] * DIM + c4 * 4);
        *(float4*)(out + (size_t)R0 * DIM + (size_t)f4 * 4) = v;
    }

    // ---- loss: term = X + d per row; fixed-point u64 atomic + ticket ----
    float term = (tid < 256) ? (rX[tid] + rdist[tid]) : 0.f;
    #pragma unroll
    for (int off = 32; off >= 1; off >>= 1) term += __shfl_xor(term, off, 64);
    if (lane == 0 && wv < 4) wred[wv] = term;
    __syncthreads();
    if (tid == 0) {
        float part = wred[0] + wred[1] + wred[2] + wred[3];
        unsigned long long q =
            (unsigned long long)((double)part * 268435456.0 + 0.5);
        atomicAdd((unsigned long long*)(ws + WS_ACC), q);
        __threadfence();
        unsigned int tk = atomicAdd((unsigned int*)(ws + WS_TICKET), 1u);
        if (tk == 255u) {
            unsigned long long tot =
                atomicAdd((unsigned long long*)(ws + WS_ACC), 0ull);
            out[(size_t)NROWS*DIM + NROWS] =
                (float)(0.25 * ((double)tot / 268435456.0)
                        / (double)((size_t)NROWS * DIM));
        }
    }
}

extern "C" void kernel_launch(void* const* d_in, const int* in_sizes, int n_in,
                              void* d_out, int out_size, void* d_ws, size_t ws_size,
                              hipStream_t stream) {
    const float* z  = (const float*)d_in[0];
    const float* ew = (const float*)d_in[1];
    float* out = (float*)d_out;
    char*  ws  = (char*)d_ws;    // ~139 KB used; every byte rewritten each call
    vq_prep <<<2,   256,  0, stream>>>(ew, ws);
    vq_fused<<<256, 1024, 0, stream>>>(z, ew, ws, out);
}

// Round 17
// 63.592 us; speedup vs baseline: 1.0840x; 1.0840x over previous
//
#include <hip/hip_runtime.h>

#define NROWS 65536
#define DIM   64
#define NE    512

// d_out is FLOAT32: [ z_q (4194304) | indices-as-float (65536) | loss (1) ]
// Scratch in d_ws (~139 KB used):
//   preSplit: 16 planes x 512 rows x 16B. plane = kt*4 + hh*2 + part
//             (part 0 = (-2e)_hi, 1 = (-2e)_lo). Conflict-free per-tile reads.
#define WS_PRESPLIT 0
#define WS_PREY     131072   // 512 x 16B: (ynorm_hi, ynorm_lo, 0...)
#define WS_YNORM    139264   // 512 x f32 np-pairwise ||e||^2
#define WS_ACC      141312   // u64 fixed-point loss accumulator
#define WS_TICKET   141320   // u32 completion ticket

typedef __attribute__((ext_vector_type(8)))  short bf16x8;
typedef __attribute__((ext_vector_type(16))) float f32x16;

static __device__ __forceinline__ unsigned short bf16rne(float x) {
    unsigned int u = __float_as_uint(x);
    u += 0x7FFFu + ((u >> 16) & 1u);            // RNE (finite inputs only)
    return (unsigned short)(u >> 16);
}
static __device__ __forceinline__ float bf16tof(unsigned short h) {
    return __uint_as_float(((unsigned int)h) << 16);
}
static __device__ __forceinline__ unsigned umn(unsigned a, unsigned b) { return a < b ? a : b; }
static __device__ __forceinline__ unsigned umx(unsigned a, unsigned b) { return a > b ? a : b; }

// K0: codebook prep (512 rows, 2 blocks) into plane layout; zero acc/ticket.
__global__ __launch_bounds__(256) void vq_prep(
    const float* __restrict__ ew, char* ws)
{
    const int r = blockIdx.x * 256 + threadIdx.x;     // 0..511
    if (r == 0) {
        *(unsigned long long*)(ws + WS_ACC)    = 0ull;
        *(unsigned long long*)(ws + WS_TICKET) = 0ull;
    }
    float a[64];
    const float4* src = (const float4*)(ew + (size_t)r * DIM);
    #pragma unroll
    for (int q = 0; q < 16; ++q) {
        float4 v = src[q];
        a[q*4+0]=v.x; a[q*4+1]=v.y; a[q*4+2]=v.z; a[q*4+3]=v.w;
    }
    // numpy-pairwise ||e||^2 (exact np f32 order)
    float rc[8];
    #pragma unroll
    for (int j = 0; j < 8; ++j) rc[j] = __fmul_rn(a[j], a[j]);
    #pragma unroll
    for (int i = 8; i < 64; i += 8)
        #pragma unroll
        for (int j = 0; j < 8; ++j)
            rc[j] = __fadd_rn(rc[j], __fmul_rn(a[i+j], a[i+j]));
    float Y = __fadd_rn(__fadd_rn(__fadd_rn(rc[0],rc[1]),__fadd_rn(rc[2],rc[3])),
                        __fadd_rn(__fadd_rn(rc[4],rc[5]),__fadd_rn(rc[6],rc[7])));
    ((float*)(ws + WS_YNORM))[r] = Y;
    unsigned short ynh = bf16rne(Y);
    unsigned short ynl = bf16rne(Y - bf16tof(ynh));
    bf16x8 py = {};
    py[0] = (short)ynh; py[1] = (short)ynl;
    *(bf16x8*)(ws + WS_PREY + r*16) = py;
    #pragma unroll
    for (int c = 0; c < 8; ++c) {        // c = kt*2 + hh
        bf16x8 h, l;
        #pragma unroll
        for (int j = 0; j < 8; ++j) {
            float x = -2.0f * a[c*8+j];
            unsigned short hb = bf16rne(x);
            h[j] = (short)hb;
            l[j] = (short)bf16rne(x - bf16tof(hb));
        }
        int kt = c >> 1, hhp = c & 1;
        int plane = kt*4 + hhp*2;
        *(bf16x8*)(ws + WS_PRESPLIT + (size_t)plane*8192 + r*16)       = h;
        *(bf16x8*)(ws + WS_PRESPLIT + (size_t)(plane+1)*8192 + r*16)   = l;
    }
}

// K1: 256 blocks x 1024 threads (16 waves). Block owns 256 z-rows.
// Wave wv: row group rg=wv>>1 (32 rows), embed half eh=wv&1 (8 tiles).
// acc biased +2.0 so distances encode as positive u32:
//   enc = (u32((2+d)*2^28) & ~511) | e   — umin order = (d, lowest e).
__global__ __launch_bounds__(1024) void vq_fused(
    const float* __restrict__ z, const float* __restrict__ ew,
    char* ws, float* out)
{
    __shared__ __align__(16) char ldsA[131072];   // 16 planes x [512][16B]
    __shared__ __align__(16) char ldsY[8192];     // preY fragments
    __shared__ uint2  mrg[256];
    __shared__ int    rwin[256];
    __shared__ float  rdist[256];
    __shared__ float  rX[256];
    __shared__ float  zs[64];
    __shared__ float  rd8[8];
    __shared__ int    ri8[8];
    __shared__ unsigned int flagbits[8];
    __shared__ float  wred[4];

    const int tid  = threadIdx.x;
    const int lane = tid & 63;
    const int wv   = tid >> 6;       // 0..15
    const int rg   = wv >> 1;        // 0..7: 32-row group
    const int eh   = wv & 1;         // embed half
    const int hh   = lane >> 5;
    const int l31  = lane & 31;
    const int R0   = blockIdx.x * 256;
    const int zrow = R0 + rg*32 + l31;
    const int eoff = eh * 256;

    if (tid < 8) flagbits[tid] = 0u;

    // ---- z fragments (split-bf16) + f32 sum-sq; B: n=lane&31, k=8*hh+j ----
    bf16x8 zh[4], zl[4];
    float xacc = 0.f;
    {
        const float* zp = z + (size_t)zrow * DIM + hh * 8;
        #pragma unroll
        for (int kt = 0; kt < 4; ++kt) {
            float4 p0 = *(const float4*)(zp + kt*16);
            float4 p1 = *(const float4*)(zp + kt*16 + 4);
            float a[8] = {p0.x,p0.y,p0.z,p0.w,p1.x,p1.y,p1.z,p1.w};
            bf16x8 hv, lv;
            #pragma unroll
            for (int j = 0; j < 8; ++j) {
                unsigned short hb = bf16rne(a[j]);
                hv[j] = (short)hb;
                lv[j] = (short)bf16rne(a[j] - bf16tof(hb));
                xacc  = fmaf(a[j], a[j], xacc);
            }
            zh[kt] = hv; zl[kt] = lv;
        }
    }

    // ---- stage preSplit+preY (139264 B = 8704 x 16B), register-lean ----
    #pragma unroll 1
    for (int i = 0; i < 9; ++i) {
        int idx = tid + 1024 * i;
        if (idx < 8704) {
            float4 v = *(const float4*)(ws + idx*16);
            if (idx < 8192) *(float4*)(ldsA + idx*16) = v;
            else            *(float4*)(ldsY + (idx - 8192)*16) = v;
        }
    }
    __syncthreads();

    const bf16x8 zero8 = {};
    bf16x8 bones = {};
    if (hh == 0) { bones[0] = (short)0x3F80; bones[1] = (short)0x3F80; }

    unsigned M1 = 0xFFFFFFFFu, M2 = 0xFFFFFFFFu;

    // ---- main loop: 8 tiles of 32 embeds; encoded tree fold ----
    #pragma unroll 1
    for (int t = 0; t < 8; ++t) {
        const int e0   = eoff + t*32;
        const int arow = e0 + l31;

        f32x16 acc;
        #pragma unroll
        for (int g = 0; g < 16; ++g) acc[g] = 2.0f;    // bias: keeps enc positive

        bf16x8 ay = zero8;
        if (hh == 0) ay = *(const bf16x8*)(ldsY + arow*16);
        acc = __builtin_amdgcn_mfma_f32_32x32x16_bf16(ay, bones, acc, 0,0,0);

        #pragma unroll
        for (int kt = 0; kt < 4; ++kt) {
            const char* pb = ldsA + (size_t)(kt*4 + hh*2)*8192 + arow*16;
            bf16x8 ah = *(const bf16x8*)(pb);
            bf16x8 al = *(const bf16x8*)(pb + 8192);
            acc = __builtin_amdgcn_mfma_f32_32x32x16_bf16(ah, zh[kt], acc, 0,0,0);
            acc = __builtin_amdgcn_mfma_f32_32x32x16_bf16(ah, zl[kt], acc, 0,0,0);
            acc = __builtin_amdgcn_mfma_f32_32x32x16_bf16(al, zh[kt], acc, 0,0,0);
        }

        // encode: value = 2 + ynorm[e] - 2 z.e  (in (0.5, 3.5))
        const int ebase = e0 + 4*hh;
        unsigned en[16];
        #pragma unroll
        for (int g = 0; g < 16; ++g) {
            unsigned e = (unsigned)(ebase + (g & 3) + 8*(g >> 2));
            unsigned u = (unsigned)(acc[g] * 268435456.0f);   // *2^28, trunc
            en[g] = (u & ~511u) | e;
        }
        // (min, second) tree over 16
        unsigned pm[8], ps[8];
        #pragma unroll
        for (int p = 0; p < 8; ++p) {
            pm[p] = umn(en[2*p], en[2*p+1]);
            ps[p] = umx(en[2*p], en[2*p+1]);
        }
        #pragma unroll
        for (int st = 4; st >= 1; st >>= 1)
            #pragma unroll
            for (int p = 0; p < 4; ++p) {
                if (p < st) {
                    unsigned hi = umx(pm[p], pm[p+st]);
                    pm[p] = umn(pm[p], pm[p+st]);
                    ps[p] = umn(umn(ps[p], ps[p+st]), hi);
                }
            }
        unsigned hi0 = umx(M1, pm[0]);
        M1 = umn(M1, pm[0]);
        M2 = umn(M2, umn(hi0, ps[0]));
    }

    // ---- intra-wave hh merge (encoded: handles value+index+tie at once) ----
    {
        unsigned oM1 = (unsigned)__shfl_xor((int)M1, 32, 64);
        unsigned oM2 = (unsigned)__shfl_xor((int)M2, 32, 64);
        unsigned hi  = umx(M1, oM1);
        M1 = umn(M1, oM1);
        M2 = umn(umn(M2, oM2), hi);
    }
    float X = xacc + __shfl_xor(xacc, 32, 64);

    // ---- cross-eh merge via LDS ----
    if (eh == 1 && hh == 0) mrg[rg*32 + l31] = make_uint2(M1, M2);
    __syncthreads();
    if (eh == 0 && hh == 0) {
        uint2 o = mrg[rg*32 + l31];
        unsigned hi = umx(M1, o.x);
        M1 = umn(M1, o.x);
        M2 = umn(umn(M2, o.y), hi);

        int   r  = rg*32 + l31;
        float s1 = (float)(M1 & ~511u) * 3.7252903e-09f - 2.0f;  // decode
        float gap = (float)((M2 & ~511u) - (M1 & ~511u)) * 3.7252903e-09f;
        float Xs = X + 1e-3f;
        float ue = __uint_as_float(__float_as_uint(Xs) & 0x7F800000u) * 1.1920929e-7f;
        bool  flag = gap < (2.0f * ue + 1.2e-5f);   // + encode quantization slop
        rwin[r]  = (int)(M1 & 511u);
        rdist[r] = s1;
        rX[r]    = X;
        if (flag) atomicOr(&flagbits[r >> 5], 1u << (r & 31));
    }
    __syncthreads();

    // ---- rescan flagged rows (np-f32 exact; 512 threads, 1 embed each) ----
    const float* yn = (const float*)(ws + WS_YNORM);
    for (int g8 = 0; g8 < 8; ++g8) {
        unsigned bits = flagbits[g8];
        while (bits) {
            int r = g8*32 + __ffs(bits) - 1;
            bits &= bits - 1;
            if (tid < 16)
                *(float4*)(zs + tid*4) =
                    *(const float4*)(z + (size_t)(R0 + r) * DIM + tid*4);
            __syncthreads();
            float rc[8];
            #pragma unroll
            for (int j = 0; j < 8; ++j) rc[j] = __fmul_rn(zs[j], zs[j]);
            #pragma unroll
            for (int i = 8; i < 64; i += 8)
                #pragma unroll
                for (int j = 0; j < 8; ++j)
                    rc[j] = __fadd_rn(rc[j], __fmul_rn(zs[i+j], zs[i+j]));
            float xn = __fadd_rn(__fadd_rn(__fadd_rn(rc[0],rc[1]),__fadd_rn(rc[2],rc[3])),
                                 __fadd_rn(__fadd_rn(rc[4],rc[5]),__fadd_rn(rc[6],rc[7])));
            float bd = 3.4e38f; int bi = NE;
            if (tid < NE) {
                const int e = tid;
                const float* ep = ew + (size_t)e * DIM;
                double m0 = 0.0, m1 = 0.0, m2 = 0.0, m3 = 0.0;
                #pragma unroll
                for (int q = 0; q < 16; ++q) {
                    float4 ev = *(const float4*)(ep + q*4);
                    m0 = fma((double)zs[q*4+0], (double)ev.x, m0);
                    m1 = fma((double)zs[q*4+1], (double)ev.y, m1);
                    m2 = fma((double)zs[q*4+2], (double)ev.z, m2);
                    m3 = fma((double)zs[q*4+3], (double)ev.w, m3);
                }
                double m = (m0 + m1) + (m2 + m3);
                float W = __fadd_rn(xn, yn[e]);
                float d = __fadd_rn(W, -(2.0f * (float)m));
                bd = d; bi = e;
            }
            #pragma unroll
            for (int off = 32; off >= 1; off >>= 1) {
                float od = __shfl_xor(bd, off, 64);
                int   oi = __shfl_xor(bi, off, 64);
                if (od < bd || (od == bd && oi < bi)) { bd = od; bi = oi; }
            }
            if (lane == 0 && wv < 8) { rd8[wv] = bd; ri8[wv] = bi; }
            __syncthreads();
            if (tid == 0) {
                float fd = rd8[0]; int fi = ri8[0];
                #pragma unroll
                for (int k = 1; k < 8; ++k)
                    if (rd8[k] < fd || (rd8[k] == fd && ri8[k] < fi)) { fd = rd8[k]; fi = ri8[k]; }
                rwin[r]  = fi;
                rdist[r] = fd;     // full np distance (includes X)
                rX[r]    = 0.f;    // no double count in loss
            }
            __syncthreads();
        }
    }

    // ---- index write (coalesced 256 floats) ----
    if (tid < 256)
        out[(size_t)NROWS*DIM + R0 + tid] = (float)rwin[tid];

    // ---- z_q write: 256 rows x 16 float4 = 4096 float4 over 1024 threads ----
    #pragma unroll
    for (int i = 0; i < 4; ++i) {
        int f4  = tid + 1024 * i;         // 0..4095
        int row = f4 >> 4;                // 0..255
        int c4  = f4 & 15;
        float4 v = *(const float4*)(ew + (size_t)rwin[row] * DIM + c4 * 4);
        *(float4*)(out + (size_t)R0 * DIM + (size_t)f4 * 4) = v;
    }

    // ---- loss: term = X + d per row; fixed-point u64 atomic + ticket ----
    float term = (tid < 256) ? (rX[tid] + rdist[tid]) : 0.f;
    #pragma unroll
    for (int off = 32; off >= 1; off >>= 1) term += __shfl_xor(term, off, 64);
    if (lane == 0 && wv < 4) wred[wv] = term;
    __syncthreads();
    if (tid == 0) {
        float part = wred[0] + wred[1] + wred[2] + wred[3];
        unsigned long long q =
            (unsigned long long)((double)part * 268435456.0 + 0.5);
        atomicAdd((unsigned long long*)(ws + WS_ACC), q);
        __threadfence();
        unsigned int tk = atomicAdd((unsigned int*)(ws + WS_TICKET), 1u);
        if (tk == 255u) {
            unsigned long long tot =
                atomicAdd((unsigned long long*)(ws + WS_ACC), 0ull);
            out[(size_t)NROWS*DIM + NROWS] =
                (float)(0.25 * ((double)tot / 268435456.0)
                        / (double)((size_t)NROWS * DIM));
        }
    }
}

extern "C" void kernel_launch(void* const* d_in, const int* in_sizes, int n_in,
                              void* d_out, int out_size, void* d_ws, size_t ws_size,
                              hipStream_t stream) {
    const float* z  = (const float*)d_in[0];
    const float* ew = (const float*)d_in[1];
    float* out = (float*)d_out;
    char*  ws  = (char*)d_ws;    // ~139 KB used; every byte rewritten each call
    vq_prep <<<2,   256,  0, stream>>>(ew, ws);
    vq_fused<<<256, 1024, 0, stream>>>(z, ew, ws, out);
}